// Round 5
// baseline (1622.074 us; speedup 1.0000x reference)
//
#include <hip/hip_runtime.h>

// Problem constants (from reference)
constexpr int NN   = 100000;    // nodes
constexpr int EE   = 6400000;   // directed edges
constexpr int FIN  = 128;
constexpr int HD   = 16;
constexpr int FOUT = 64;

// Bucketing parameters
constexpr int CB     = 9;                          // bucket = dst >> 9
constexpr int BUKN   = 1 << CB;                    // 512 nodes per bucket
constexpr int NBUK   = (NN + BUKN - 1) >> CB;      // 196 buckets
constexpr int KSUB   = 4;                          // sub-WGs per bucket for aggregation
constexpr int CHUNK  = 4096;                       // edges per WG in coarse scatter
constexpr int NCHUNK = (EE + CHUNK - 1) / CHUNK;   // 1563
constexpr int PSTRIDE = BUKN * HD;                 // 8192 floats per (bucket,sub) partial

// ---------------------------------------------------------------------------
// zero chist[256] and degi[NN]
__global__ __launch_bounds__(256) void zero_kernel(int* __restrict__ chist,
                                                   int* __restrict__ degi) {
    int i = blockIdx.x * 256 + threadIdx.x;
    if (i < 256) chist[i] = 0;
    int v = i - 256;
    if (v >= 0 && v < NN) degi[v] = 0;
}

// Coarse histogram over dst>>CB, LDS-staged
__global__ __launch_bounds__(256) void coarse_hist_kernel(const int* __restrict__ dst,
                                                          int* __restrict__ chist) {
    __shared__ int h[256];
    int tid = threadIdx.x;
    h[tid] = 0;
    __syncthreads();
    int stride = gridDim.x * 256;
    for (int i = blockIdx.x * 256 + tid; i < EE / 4; i += stride) {
        int4 d4 = reinterpret_cast<const int4*>(dst)[i];
        atomicAdd(&h[d4.x >> CB], 1);
        atomicAdd(&h[d4.y >> CB], 1);
        atomicAdd(&h[d4.z >> CB], 1);
        atomicAdd(&h[d4.w >> CB], 1);
    }
    __syncthreads();
    if (h[tid]) atomicAdd(&chist[tid], h[tid]);
}

// Exclusive scan of 256 coarse bins -> cofs[257]; bcur = working cursors
__global__ __launch_bounds__(256) void scan_coarse_kernel(const int* __restrict__ chist,
                                                          int* __restrict__ cofs,
                                                          int* __restrict__ bcur) {
    __shared__ int s[256];
    int tid = threadIdx.x;
    int val = chist[tid];
    s[tid] = val;
    __syncthreads();
    for (int st = 1; st < 256; st <<= 1) {
        int add = (tid >= st) ? s[tid - st] : 0;
        __syncthreads();
        s[tid] += add;
        __syncthreads();
    }
    int excl = s[tid] - val;
    cofs[tid] = excl;
    bcur[tid] = excl;
    if (tid == 255) cofs[256] = s[255];
}

// Coarse scatter: rank chunk's edges by bucket in LDS, claim global bases,
// write packed (dstLow<<20 | src) u32s in coalesced per-bucket runs.
__global__ __launch_bounds__(256) void coarse_scatter_kernel(const int* __restrict__ src,
                                                             const int* __restrict__ dst,
                                                             int* __restrict__ bcur,
                                                             unsigned int* __restrict__ pair) {
    __shared__ int h[256];
    __shared__ int exc[256];
    __shared__ int cur[256];
    __shared__ int gbase[256];
    __shared__ unsigned int stage[CHUNK];       // 16 KB
    __shared__ unsigned char binOf[CHUNK];      // 4 KB
    int tid = threadIdx.x;
    int e0 = blockIdx.x * CHUNK;
    int n = min(CHUNK, EE - e0);

    h[tid] = 0;
    __syncthreads();
    for (int i = tid; i < n; i += 256) atomicAdd(&h[dst[e0 + i] >> CB], 1);
    __syncthreads();
    {
        int val = h[tid];
        exc[tid] = val;
        __syncthreads();
        for (int st = 1; st < 256; st <<= 1) {
            int add = (tid >= st) ? exc[tid - st] : 0;
            __syncthreads();
            exc[tid] += add;
            __syncthreads();
        }
        exc[tid] -= val;
    }
    cur[tid] = exc[tid];
    gbase[tid] = atomicAdd(&bcur[tid], h[tid]);   // per-bucket global base
    __syncthreads();
    for (int i = tid; i < n; i += 256) {
        int d = dst[e0 + i];
        int s = src[e0 + i];
        int b = d >> CB;
        int p = atomicAdd(&cur[b], 1);
        stage[p] = (unsigned int)s | ((unsigned int)(d & (BUKN - 1)) << 20);
        binOf[p] = (unsigned char)b;
    }
    __syncthreads();
    for (int i = tid; i < n; i += 256) {
        int b = binOf[i];
        pair[gbase[b] + (i - exc[b])] = stage[i];
    }
}

// ---------------------------------------------------------------------------
// Per-bucket degree: LDS histogram of dstLow over a bucket slice, add to degi
// ---------------------------------------------------------------------------
__global__ __launch_bounds__(256) void deg_bucket_kernel(const unsigned int* __restrict__ pair,
                                                         const int* __restrict__ cofs,
                                                         int* __restrict__ degi) {
    __shared__ int hd[BUKN];  // 2 KB
    int tid = threadIdx.x;
    int b = blockIdx.x >> 2;
    int k = blockIdx.x & 3;
    for (int i = tid; i < BUKN; i += 256) hd[i] = 0;
    __syncthreads();
    int lo = cofs[b], hi = cofs[b + 1];
    int len = hi - lo;
    int s0 = lo + (int)(((long long)len * k) >> 2);
    int s1 = lo + (int)(((long long)len * (k + 1)) >> 2);
    for (int i = s0 + tid; i < s1; i += 256)
        atomicAdd(&hd[pair[i] >> 20], 1);
    __syncthreads();
    int v0 = b << CB;
    for (int i = tid; i < BUKN; i += 256) {
        int v = v0 + i;
        if (hd[i] && v < NN) atomicAdd(&degi[v], hd[i]);
    }
}

__global__ __launch_bounds__(256) void dinv_kernel(const int* __restrict__ degi,
                                                   float* __restrict__ dinv) {
    int v = blockIdx.x * 256 + threadIdx.x;
    if (v < NN) dinv[v] = rsqrtf((float)(degi[v] + 1));   // +1 self-loop
}

// ---------------------------------------------------------------------------
// Layer-1 transform: t1[v,:] = (x[v,:] @ W1) * dinv[v]
// ---------------------------------------------------------------------------
__global__ __launch_bounds__(256) void gemm1_kernel(const float* __restrict__ x,
                                                    const float* __restrict__ W1,
                                                    const float* __restrict__ dinv,
                                                    float* __restrict__ t1) {
    __shared__ float W1s[FIN][HD];        // 8 KB
    __shared__ float xs[16][FIN + 1];
    int tid = threadIdx.x;
    int nodeBase = blockIdx.x * 16;

    for (int i = tid; i < FIN * HD; i += 256) W1s[i >> 4][i & 15] = W1[i];
    for (int i = tid; i < 16 * FIN; i += 256) {
        int r = i >> 7, c = i & 127;
        int v = nodeBase + r;
        xs[r][c] = (v < NN) ? x[(long long)v * FIN + c] : 0.0f;
    }
    __syncthreads();

    int r = tid >> 4, j = tid & 15;
    int v = nodeBase + r;
    if (v < NN) {
        float acc = 0.0f;
        #pragma unroll
        for (int k = 0; k < FIN; ++k) acc += xs[r][k] * W1s[k][j];
        t1[v * HD + j] = acc * dinv[v];
    }
}

// ---------------------------------------------------------------------------
// Aggregation partial: one (bucket, sub) per WG. Stream the bucket slice,
// gather t[src,:], ds_add_f32 into LDS acc[dstLow][:]. Write partial to global.
// 16 threads per edge (j = feature), 16 edges per block-iteration, unroll 4.
// ---------------------------------------------------------------------------
__global__ __launch_bounds__(256) void agg_partial_kernel(const unsigned int* __restrict__ pair,
                                                          const int* __restrict__ cofs,
                                                          const float* __restrict__ t,
                                                          float* __restrict__ part) {
    __shared__ float acc[BUKN][HD + 1];   // 512x17x4 = 34.8 KB (pad breaks bank clustering)
    int tid = threadIdx.x;
    int b = blockIdx.x >> 2;
    int k = blockIdx.x & 3;

    for (int i = tid; i < BUKN * (HD + 1); i += 256) (&acc[0][0])[i] = 0.0f;
    __syncthreads();

    int lo = cofs[b], hi = cofs[b + 1];
    int len = hi - lo;
    int s0 = lo + (int)(((long long)len * k) >> 2);
    int s1 = lo + (int)(((long long)len * (k + 1)) >> 2);

    int j = tid & 15;
    int i = s0 + (tid >> 4);
    for (; i + 48 < s1; i += 64) {            // 4-deep MLP
        unsigned int p0 = pair[i];
        unsigned int p1 = pair[i + 16];
        unsigned int p2 = pair[i + 32];
        unsigned int p3 = pair[i + 48];
        float v0 = t[(p0 & 0xFFFFFu) * HD + j];
        float v1 = t[(p1 & 0xFFFFFu) * HD + j];
        float v2 = t[(p2 & 0xFFFFFu) * HD + j];
        float v3 = t[(p3 & 0xFFFFFu) * HD + j];
        atomicAdd(&acc[p0 >> 20][j], v0);
        atomicAdd(&acc[p1 >> 20][j], v1);
        atomicAdd(&acc[p2 >> 20][j], v2);
        atomicAdd(&acc[p3 >> 20][j], v3);
    }
    for (; i < s1; i += 16) {
        unsigned int p = pair[i];
        atomicAdd(&acc[p >> 20][j], t[(p & 0xFFFFFu) * HD + j]);
    }
    __syncthreads();

    // coalesced partial write: part[(b*4+k)*8192 + n*16 + j]
    float* pw = part + ((b << 2) | k) * PSTRIDE;
    for (int n = tid >> 4; n < BUKN; n += 16)
        pw[n * HD + j] = acc[n][j];
}

// ---------------------------------------------------------------------------
// reduce1: agg1 = sum of 4 partials + self(t1);  t2 = relu(dinv*agg1 + b1)*dinv
// ---------------------------------------------------------------------------
__global__ __launch_bounds__(256) void reduce1_kernel(const float* __restrict__ part,
                                                      const float* __restrict__ t1,
                                                      const float* __restrict__ dinv,
                                                      const float* __restrict__ b1,
                                                      float* __restrict__ t2) {
    int idx = blockIdx.x * 256 + threadIdx.x;   // < NN*HD (grid exact: 6250*256)
    if (idx >= NN * HD) return;
    int v = idx >> 4, j = idx & 15;
    int b = v >> CB, n = v & (BUKN - 1);
    const float* pb = part + (b << 2) * PSTRIDE + n * HD + j;
    float s = pb[0] + pb[PSTRIDE] + pb[2 * PSTRIDE] + pb[3 * PSTRIDE] + t1[idx];
    float di = dinv[v];
    float h = fmaxf(di * s + b1[j], 0.0f);
    t2[idx] = h * di;
}

// ---------------------------------------------------------------------------
// reduce2 + gemm2: agg2 = sum partials + self(t2);  out = (dinv*agg2) @ W2 + b2
// 64 nodes per WG.
// ---------------------------------------------------------------------------
__global__ __launch_bounds__(256) void reduce2_gemm2_kernel(const float* __restrict__ part,
                                                            const float* __restrict__ t2,
                                                            const float* __restrict__ dinv,
                                                            const float* __restrict__ W2,
                                                            const float* __restrict__ b2,
                                                            float* __restrict__ out) {
    __shared__ float W2s[HD][FOUT];    // 4 KB
    __shared__ float sA[64][HD + 1];   // 4.2 KB
    int tid = threadIdx.x;
    int nodeBase = blockIdx.x * 64;

    for (int i = tid; i < HD * FOUT; i += 256) W2s[i >> 6][i & 63] = W2[i];
    for (int i = tid; i < 64 * HD; i += 256) {
        int vr = i >> 4, j = i & 15;
        int v = nodeBase + vr;
        float s = 0.0f;
        if (v < NN) {
            int b = v >> CB, n = v & (BUKN - 1);
            const float* pb = part + (b << 2) * PSTRIDE + n * HD + j;
            s = (pb[0] + pb[PSTRIDE] + pb[2 * PSTRIDE] + pb[3 * PSTRIDE] + t2[v * HD + j]) * dinv[v];
        }
        sA[vr][j] = s;
    }
    __syncthreads();

    int jo = tid & 63;
    int v0 = tid >> 6;                 // 0..3
    for (int vr = v0; vr < 64; vr += 4) {
        int v = nodeBase + vr;
        if (v < NN) {
            float acc = b2[jo];
            #pragma unroll
            for (int k = 0; k < HD; ++k) acc += sA[vr][k] * W2s[k][jo];
            out[(long long)v * FOUT + jo] = acc;
        }
    }
}

// ---------------------------------------------------------------------------
extern "C" void kernel_launch(void* const* d_in, const int* in_sizes, int n_in,
                              void* d_out, int out_size, void* d_ws, size_t ws_size,
                              hipStream_t stream) {
    const float* x  = (const float*)d_in[0];
    const int*   ei = (const int*)d_in[1];      // [2, E] row-major
    const float* W1 = (const float*)d_in[2];
    const float* b1 = (const float*)d_in[3];
    const float* W2 = (const float*)d_in[4];
    const float* b2 = (const float*)d_in[5];
    float* out = (float*)d_out;

    const int* src = ei;
    const int* dst = ei + EE;

    // workspace layout (~65 MB)
    int* wsI    = (int*)d_ws;
    int* chist  = wsI;                     // 256
    int* cofs   = chist + 256;             // 257 (pad 512)
    int* bcur   = cofs + 512;              // 256
    int* degi   = bcur + 256;              // N
    float* dinv = (float*)(degi + NN);     // N
    unsigned int* pair = (unsigned int*)(dinv + NN);       // E  (25.6 MB)
    float* part = (float*)(pair + EE);     // NBUK*KSUB*PSTRIDE = 6.42M f (25.7 MB)
    float* t1   = part + NBUK * KSUB * PSTRIDE;            // N*HD
    float* t2   = t1 + NN * HD;            // N*HD

    // bucket sort by dst>>9 (packed dstLow|src), no CSR
    zero_kernel<<<(256 + NN + 255) / 256, 256, 0, stream>>>(chist, degi);
    coarse_hist_kernel<<<1024, 256, 0, stream>>>(dst, chist);
    scan_coarse_kernel<<<1, 256, 0, stream>>>(chist, cofs, bcur);
    coarse_scatter_kernel<<<NCHUNK, 256, 0, stream>>>(src, dst, bcur, pair);

    // degrees -> dinv
    deg_bucket_kernel<<<NBUK * KSUB, 256, 0, stream>>>(pair, cofs, degi);
    dinv_kernel<<<(NN + 255) / 256, 256, 0, stream>>>(degi, dinv);

    // layer 1: transform, LDS-bucket aggregate, fused epilogue
    gemm1_kernel<<<(NN + 15) / 16, 256, 0, stream>>>(x, W1, dinv, t1);
    agg_partial_kernel<<<NBUK * KSUB, 256, 0, stream>>>(pair, cofs, t1, part);
    reduce1_kernel<<<(NN * HD + 255) / 256, 256, 0, stream>>>(part, t1, dinv, b1, t2);

    // layer 2: aggregate in hidden dim, fused W2 transform
    agg_partial_kernel<<<NBUK * KSUB, 256, 0, stream>>>(pair, cofs, t2, part);
    reduce2_gemm2_kernel<<<(NN + 63) / 64, 256, 0, stream>>>(part, t2, dinv, W2, b2, out);
}

// Round 6
// 468.635 us; speedup vs baseline: 3.4613x; 3.4613x over previous
//
#include <hip/hip_runtime.h>

// Problem constants (from reference)
constexpr int NN   = 100000;    // nodes
constexpr int EE   = 6400000;   // directed edges
constexpr int FIN  = 128;
constexpr int HD   = 16;
constexpr int FOUT = 64;

// Bucketing parameters
constexpr int CB     = 7;                          // bucket = dst >> 7
constexpr int BUKN   = 1 << CB;                    // 128 nodes per bucket
constexpr int NBUK   = (NN + BUKN - 1) >> CB;      // 782 buckets
constexpr int NB     = 800;                        // padded bin-array size (LDS)
constexpr int NBPAD  = 1024;                       // padded bin count (global arrays)
constexpr int CHUNK  = 4096;                       // edges per WG in coarse scatter
constexpr int NCHUNK = (EE + CHUNK - 1) / CHUNK;   // 1563

// ---------------------------------------------------------------------------
__global__ __launch_bounds__(256) void zero_chist_kernel(int* __restrict__ chist) {
    int i = blockIdx.x * 256 + threadIdx.x;
    if (i < NBPAD) chist[i] = 0;
}

// Coarse histogram over dst>>CB, LDS-staged
__global__ __launch_bounds__(256) void coarse_hist_kernel(const int* __restrict__ dst,
                                                          int* __restrict__ chist) {
    __shared__ int h[NBPAD];
    int tid = threadIdx.x;
    for (int i = tid; i < NBPAD; i += 256) h[i] = 0;
    __syncthreads();
    int stride = gridDim.x * 256;
    for (int i = blockIdx.x * 256 + tid; i < EE / 4; i += stride) {
        int4 d4 = reinterpret_cast<const int4*>(dst)[i];
        atomicAdd(&h[d4.x >> CB], 1);
        atomicAdd(&h[d4.y >> CB], 1);
        atomicAdd(&h[d4.z >> CB], 1);
        atomicAdd(&h[d4.w >> CB], 1);
    }
    __syncthreads();
    for (int i = tid; i < NBPAD; i += 256)
        if (h[i]) atomicAdd(&chist[i], h[i]);
}

// Exclusive scan of NBPAD coarse bins (4 per thread) -> cofs[NBPAD+1]; bcur copy
__global__ __launch_bounds__(256) void scan_coarse_kernel(const int* __restrict__ chist,
                                                          int* __restrict__ cofs,
                                                          int* __restrict__ bcur) {
    __shared__ int ps[256];
    int tid = threadIdx.x;
    int a0 = chist[4 * tid], a1 = chist[4 * tid + 1];
    int a2 = chist[4 * tid + 2], a3 = chist[4 * tid + 3];
    int tot = a0 + a1 + a2 + a3;
    ps[tid] = tot;
    __syncthreads();
    for (int st = 1; st < 256; st <<= 1) {
        int add = (tid >= st) ? ps[tid - st] : 0;
        __syncthreads();
        ps[tid] += add;
        __syncthreads();
    }
    int base = ps[tid] - tot;
    cofs[4 * tid] = base;
    cofs[4 * tid + 1] = base + a0;
    cofs[4 * tid + 2] = base + a0 + a1;
    cofs[4 * tid + 3] = base + a0 + a1 + a2;
    bcur[4 * tid] = base;
    bcur[4 * tid + 1] = base + a0;
    bcur[4 * tid + 2] = base + a0 + a1;
    bcur[4 * tid + 3] = base + a0 + a1 + a2;
    if (tid == 255) cofs[NBPAD] = ps[255];
}

// Coarse scatter: rank chunk's edges by bucket in LDS, claim global bases,
// write packed (dstLow<<20 | src) u32s in coalesced per-bucket runs.
__global__ __launch_bounds__(256) void coarse_scatter_kernel(const int* __restrict__ src,
                                                             const int* __restrict__ dst,
                                                             int* __restrict__ bcur,
                                                             unsigned int* __restrict__ pair) {
    __shared__ int h[NB];
    __shared__ int exc[NB];
    __shared__ int cur[NB];
    __shared__ int gbase[NB];
    __shared__ int ps[256];
    __shared__ unsigned int stage[CHUNK];        // 16 KB
    __shared__ unsigned short binOf[CHUNK];      // 8 KB
    int tid = threadIdx.x;
    int e0 = blockIdx.x * CHUNK;
    int n = min(CHUNK, EE - e0);

    for (int i = tid; i < NB; i += 256) h[i] = 0;
    __syncthreads();
    for (int i = tid; i < n; i += 256) atomicAdd(&h[dst[e0 + i] >> CB], 1);
    __syncthreads();
    // blocked exclusive scan: thread t owns bins 4t..4t+3 (guard >= NB)
    int i0 = 4 * tid;
    int a0 = (i0 + 0 < NB) ? h[i0 + 0] : 0;
    int a1 = (i0 + 1 < NB) ? h[i0 + 1] : 0;
    int a2 = (i0 + 2 < NB) ? h[i0 + 2] : 0;
    int a3 = (i0 + 3 < NB) ? h[i0 + 3] : 0;
    int tot = a0 + a1 + a2 + a3;
    ps[tid] = tot;
    __syncthreads();
    for (int st = 1; st < 256; st <<= 1) {
        int add = (tid >= st) ? ps[tid - st] : 0;
        __syncthreads();
        ps[tid] += add;
        __syncthreads();
    }
    int base = ps[tid] - tot;
    if (i0 + 0 < NB) { exc[i0 + 0] = base;                cur[i0 + 0] = base; }
    if (i0 + 1 < NB) { exc[i0 + 1] = base + a0;           cur[i0 + 1] = base + a0; }
    if (i0 + 2 < NB) { exc[i0 + 2] = base + a0 + a1;      cur[i0 + 2] = base + a0 + a1; }
    if (i0 + 3 < NB) { exc[i0 + 3] = base + a0 + a1 + a2; cur[i0 + 3] = base + a0 + a1 + a2; }
    __syncthreads();
    for (int b = tid; b < NB; b += 256)
        gbase[b] = h[b] ? atomicAdd(&bcur[b], h[b]) : 0;
    __syncthreads();
    // rank & stage
    for (int i = tid; i < n; i += 256) {
        int d = dst[e0 + i];
        int s = src[e0 + i];
        int b = d >> CB;
        int p = atomicAdd(&cur[b], 1);
        stage[p] = (unsigned int)s | ((unsigned int)(d & (BUKN - 1)) << 20);
        binOf[p] = (unsigned short)b;
    }
    __syncthreads();
    // coalesced write-out per bucket run
    for (int i = tid; i < n; i += 256) {
        int b = binOf[i];
        pair[gbase[b] + (i - exc[b])] = stage[i];
    }
}

// ---------------------------------------------------------------------------
// Per-bucket CSR build: histogram 128 local bins, scan, emit rowptr/deg/dinv,
// place srcs within the bucket's contiguous 32KB window. 782 WGs.
// ---------------------------------------------------------------------------
__global__ __launch_bounds__(256) void bucket_build_kernel(const unsigned int* __restrict__ pair,
                                                           const int* __restrict__ cofs,
                                                           int* __restrict__ rowptr,
                                                           int* __restrict__ degi,
                                                           float* __restrict__ dinv,
                                                           int* __restrict__ srcs) {
    __shared__ int h[BUKN];
    __shared__ int sc[BUKN];
    __shared__ int cur[BUKN];
    int tid = threadIdx.x;
    int b = blockIdx.x;
    int lo = cofs[b], hi = cofs[b + 1];

    if (tid < BUKN) h[tid] = 0;
    __syncthreads();
    for (int i = lo + tid; i < hi; i += 256)
        atomicAdd(&h[pair[i] >> 20], 1);
    __syncthreads();
    if (tid < BUKN) sc[tid] = h[tid];
    __syncthreads();
    for (int st = 1; st < BUKN; st <<= 1) {
        int add = (tid >= st && tid < BUKN) ? sc[tid - st] : 0;
        __syncthreads();
        if (tid < BUKN) sc[tid] += add;
        __syncthreads();
    }
    if (tid < BUKN) {
        int excl = sc[tid] - h[tid];
        int v = (b << CB) + tid;
        cur[tid] = lo + excl;
        if (v < NN) {
            rowptr[v] = lo + excl;
            degi[v]   = h[tid];
            dinv[v]   = rsqrtf((float)(h[tid] + 1));   // +1 self-loop
        }
    }
    __syncthreads();
    for (int i = lo + tid; i < hi; i += 256) {
        unsigned int pd = pair[i];
        int p = atomicAdd(&cur[pd >> 20], 1);
        srcs[p] = (int)(pd & 0xFFFFFu);
    }
}

// ---------------------------------------------------------------------------
// Layer-1 transform: t1[v,:] = (x[v,:] @ W1) * dinv[v]
// ---------------------------------------------------------------------------
__global__ __launch_bounds__(256) void gemm1_kernel(const float* __restrict__ x,
                                                    const float* __restrict__ W1,
                                                    const float* __restrict__ dinv,
                                                    float* __restrict__ t1) {
    __shared__ float W1s[FIN][HD];        // 8 KB
    __shared__ float xs[16][FIN + 1];
    int tid = threadIdx.x;
    int nodeBase = blockIdx.x * 16;

    for (int i = tid; i < FIN * HD; i += 256) W1s[i >> 4][i & 15] = W1[i];
    for (int i = tid; i < 16 * FIN; i += 256) {
        int r = i >> 7, c = i & 127;
        int v = nodeBase + r;
        xs[r][c] = (v < NN) ? x[(long long)v * FIN + c] : 0.0f;
    }
    __syncthreads();

    int r = tid >> 4, j = tid & 15;
    int v = nodeBase + r;
    if (v < NN) {
        float acc = 0.0f;
        #pragma unroll
        for (int k = 0; k < FIN; ++k) acc += xs[r][k] * W1s[k][j];
        t1[v * HD + j] = acc * dinv[v];
    }
}

// ---------------------------------------------------------------------------
// Gather-aggregate, wave per node. mode 1: fused layer-1 epilogue
// (out = relu(di*(acc+self)+b1)*di); mode 0: raw (out = acc+self).
// ---------------------------------------------------------------------------
__global__ __launch_bounds__(256) void gather_kernel(const int* __restrict__ rowptr,
                                                     const int* __restrict__ degi,
                                                     const int* __restrict__ srcs,
                                                     const float* __restrict__ t,
                                                     const float* __restrict__ dinv,
                                                     const float* __restrict__ b1,
                                                     float* __restrict__ outb,
                                                     int mode) {
    int gw = (blockIdx.x * 256 + threadIdx.x) >> 6;   // node = global wave id
    int lane = threadIdx.x & 63;
    if (gw >= NN) return;
    int start = rowptr[gw];
    int cnt   = degi[gw];
    int j   = lane & 15;
    int sub = lane >> 4;       // 0..3
    float acc = 0.0f;
    int e = sub;
    for (; e + 12 < cnt; e += 16) {      // 4-deep MLP
        int s0 = srcs[start + e];
        int s1 = srcs[start + e + 4];
        int s2 = srcs[start + e + 8];
        int s3 = srcs[start + e + 12];
        float a0 = t[s0 * HD + j];
        float a1 = t[s1 * HD + j];
        float a2 = t[s2 * HD + j];
        float a3 = t[s3 * HD + j];
        acc += a0 + a1 + a2 + a3;
    }
    for (; e < cnt; e += 4) acc += t[srcs[start + e] * HD + j];
    acc += __shfl_xor(acc, 16);
    acc += __shfl_xor(acc, 32);
    if (sub == 0) {
        float s = acc + t[gw * HD + j];          // + self-loop
        if (mode) {
            float di = dinv[gw];
            outb[gw * HD + j] = fmaxf(di * s + b1[j], 0.0f) * di;
        } else {
            outb[gw * HD + j] = s;
        }
    }
}

// ---------------------------------------------------------------------------
// gemm2: out[v,:] = (dinv[v]*agg2[v,:]) @ W2 + b2   (64 nodes per WG)
// ---------------------------------------------------------------------------
__global__ __launch_bounds__(256) void gemm2_kernel(const float* __restrict__ agg2,
                                                    const float* __restrict__ dinv,
                                                    const float* __restrict__ W2,
                                                    const float* __restrict__ b2,
                                                    float* __restrict__ out) {
    __shared__ float W2s[HD][FOUT];    // 4 KB
    __shared__ float sA[64][HD + 1];
    int tid = threadIdx.x;
    int nodeBase = blockIdx.x * 64;

    for (int i = tid; i < HD * FOUT; i += 256) W2s[i >> 6][i & 63] = W2[i];
    for (int i = tid; i < 64 * HD; i += 256) {
        int vr = i >> 4, j = i & 15;
        int v = nodeBase + vr;
        sA[vr][j] = (v < NN) ? agg2[v * HD + j] * dinv[v] : 0.0f;
    }
    __syncthreads();

    int jo = tid & 63;
    int v0 = tid >> 6;                 // 0..3
    for (int vr = v0; vr < 64; vr += 4) {
        int v = nodeBase + vr;
        if (v < NN) {
            float acc = b2[jo];
            #pragma unroll
            for (int k = 0; k < HD; ++k) acc += sA[vr][k] * W2s[k][jo];
            out[(long long)v * FOUT + jo] = acc;
        }
    }
}

// ---------------------------------------------------------------------------
extern "C" void kernel_launch(void* const* d_in, const int* in_sizes, int n_in,
                              void* d_out, int out_size, void* d_ws, size_t ws_size,
                              hipStream_t stream) {
    const float* x  = (const float*)d_in[0];
    const int*   ei = (const int*)d_in[1];      // [2, E] row-major
    const float* W1 = (const float*)d_in[2];
    const float* b1 = (const float*)d_in[3];
    const float* W2 = (const float*)d_in[4];
    const float* b2 = (const float*)d_in[5];
    float* out = (float*)d_out;

    const int* src = ei;
    const int* dst = ei + EE;

    // workspace layout (~65 MB)
    int* wsI    = (int*)d_ws;
    int* chist  = wsI;                     // NBPAD
    int* cofs   = chist + NBPAD;           // NBPAD+1 (pad to NBPAD+32)
    int* bcur   = cofs + NBPAD + 32;       // NBPAD
    int* rowptr = bcur + NBPAD;            // N
    int* degi   = rowptr + NN;             // N
    float* dinv = (float*)(degi + NN);     // N
    unsigned int* pair = (unsigned int*)(dinv + NN);  // E  (25.6 MB)
    int* srcs   = (int*)(pair + EE);       // E  (25.6 MB)
    float* t1   = (float*)(srcs + EE);     // N*HD
    float* t2   = t1 + NN * HD;            // N*HD
    float* agg2 = t1;                      // alias: t1 dead after gather1

    // bucket sort by dst>>7 (packed dstLow|src) + per-bucket CSR
    zero_chist_kernel<<<(NBPAD + 255) / 256, 256, 0, stream>>>(chist);
    coarse_hist_kernel<<<1024, 256, 0, stream>>>(dst, chist);
    scan_coarse_kernel<<<1, 256, 0, stream>>>(chist, cofs, bcur);
    coarse_scatter_kernel<<<NCHUNK, 256, 0, stream>>>(src, dst, bcur, pair);
    bucket_build_kernel<<<NBUK, 256, 0, stream>>>(pair, cofs, rowptr, degi, dinv, srcs);

    // layer 1: transform, gather with fused epilogue -> t2
    gemm1_kernel<<<(NN + 15) / 16, 256, 0, stream>>>(x, W1, dinv, t1);
    gather_kernel<<<(NN + 3) / 4, 256, 0, stream>>>(rowptr, degi, srcs, t1, dinv, b1, t2, 1);
    // layer 2: raw gather -> agg2, then fused dinv-scale + W2 transform
    gather_kernel<<<(NN + 3) / 4, 256, 0, stream>>>(rowptr, degi, srcs, t2, dinv, b1, agg2, 0);
    gemm2_kernel<<<(NN + 63) / 64, 256, 0, stream>>>(agg2, dinv, W2, b2, out);
}

// Round 8
// 442.871 us; speedup vs baseline: 3.6626x; 1.0582x over previous
//
#include <hip/hip_runtime.h>
#include <hip/hip_fp16.h>

// Problem constants (from reference)
constexpr int NN   = 100000;    // nodes
constexpr int EE   = 6400000;   // directed edges
constexpr int FIN  = 128;
constexpr int HD   = 16;
constexpr int FOUT = 64;

// Bucketing parameters
constexpr int CB     = 7;                          // bucket = dst >> 7
constexpr int BUKN   = 1 << CB;                    // 128 nodes per bucket
constexpr int NBUK   = (NN + BUKN - 1) >> CB;      // 782 buckets
constexpr int NB     = 800;                        // padded bin-array size (LDS)
constexpr int NBPAD  = 1024;                       // padded bin count (global arrays)
constexpr int CHUNK  = 2048;                       // edges per WG in coarse scatter
constexpr int NCHUNK = (EE + CHUNK - 1) / CHUNK;   // 3125

// ---------------------------------------------------------------------------
__global__ __launch_bounds__(256) void zero_chist_kernel(int* __restrict__ chist) {
    int i = blockIdx.x * 256 + threadIdx.x;
    if (i < NBPAD) chist[i] = 0;
}

// Coarse histogram over dst>>CB, LDS-staged
__global__ __launch_bounds__(256) void coarse_hist_kernel(const int* __restrict__ dst,
                                                          int* __restrict__ chist) {
    __shared__ int h[NBPAD];
    int tid = threadIdx.x;
    for (int i = tid; i < NBPAD; i += 256) h[i] = 0;
    __syncthreads();
    int stride = gridDim.x * 256;
    for (int i = blockIdx.x * 256 + tid; i < EE / 4; i += stride) {
        int4 d4 = reinterpret_cast<const int4*>(dst)[i];
        atomicAdd(&h[d4.x >> CB], 1);
        atomicAdd(&h[d4.y >> CB], 1);
        atomicAdd(&h[d4.z >> CB], 1);
        atomicAdd(&h[d4.w >> CB], 1);
    }
    __syncthreads();
    for (int i = tid; i < NBPAD; i += 256)
        if (h[i]) atomicAdd(&chist[i], h[i]);
}

// Exclusive scan of NBPAD coarse bins (4 per thread) -> cofs[NBPAD+1]; bcur copy
__global__ __launch_bounds__(256) void scan_coarse_kernel(const int* __restrict__ chist,
                                                          int* __restrict__ cofs,
                                                          int* __restrict__ bcur) {
    __shared__ int ps[256];
    int tid = threadIdx.x;
    int a0 = chist[4 * tid], a1 = chist[4 * tid + 1];
    int a2 = chist[4 * tid + 2], a3 = chist[4 * tid + 3];
    int tot = a0 + a1 + a2 + a3;
    ps[tid] = tot;
    __syncthreads();
    for (int st = 1; st < 256; st <<= 1) {
        int add = (tid >= st) ? ps[tid - st] : 0;
        __syncthreads();
        ps[tid] += add;
        __syncthreads();
    }
    int base = ps[tid] - tot;
    cofs[4 * tid] = base;
    cofs[4 * tid + 1] = base + a0;
    cofs[4 * tid + 2] = base + a0 + a1;
    cofs[4 * tid + 3] = base + a0 + a1 + a2;
    bcur[4 * tid] = base;
    bcur[4 * tid + 1] = base + a0;
    bcur[4 * tid + 2] = base + a0 + a1;
    bcur[4 * tid + 3] = base + a0 + a1 + a2;
    if (tid == 255) cofs[NBPAD] = ps[255];
}

// Coarse scatter: rank chunk's edges by bucket in LDS, claim global bases,
// write packed (dstLow<<20 | src) u32s in coalesced per-bucket runs.
__global__ __launch_bounds__(256) void coarse_scatter_kernel(const int* __restrict__ src,
                                                             const int* __restrict__ dst,
                                                             int* __restrict__ bcur,
                                                             unsigned int* __restrict__ pair) {
    __shared__ int h[NB];
    __shared__ int exc[NB];
    __shared__ int cur[NB];
    __shared__ int gbase[NB];
    __shared__ int ps[256];
    __shared__ unsigned int stage[CHUNK];        // 8 KB
    __shared__ unsigned short binOf[CHUNK];      // 4 KB
    int tid = threadIdx.x;
    int e0 = blockIdx.x * CHUNK;
    int n = min(CHUNK, EE - e0);

    for (int i = tid; i < NB; i += 256) h[i] = 0;
    __syncthreads();
    for (int i = tid; i < n; i += 256) atomicAdd(&h[dst[e0 + i] >> CB], 1);
    __syncthreads();
    // blocked exclusive scan: thread t owns bins 4t..4t+3 (guard >= NB)
    int i0 = 4 * tid;
    int a0 = (i0 + 0 < NB) ? h[i0 + 0] : 0;
    int a1 = (i0 + 1 < NB) ? h[i0 + 1] : 0;
    int a2 = (i0 + 2 < NB) ? h[i0 + 2] : 0;
    int a3 = (i0 + 3 < NB) ? h[i0 + 3] : 0;
    int tot = a0 + a1 + a2 + a3;
    ps[tid] = tot;
    __syncthreads();
    for (int st = 1; st < 256; st <<= 1) {
        int add = (tid >= st) ? ps[tid - st] : 0;
        __syncthreads();
        ps[tid] += add;
        __syncthreads();
    }
    int base = ps[tid] - tot;
    if (i0 + 0 < NB) { exc[i0 + 0] = base;                cur[i0 + 0] = base; }
    if (i0 + 1 < NB) { exc[i0 + 1] = base + a0;           cur[i0 + 1] = base + a0; }
    if (i0 + 2 < NB) { exc[i0 + 2] = base + a0 + a1;      cur[i0 + 2] = base + a0 + a1; }
    if (i0 + 3 < NB) { exc[i0 + 3] = base + a0 + a1 + a2; cur[i0 + 3] = base + a0 + a1 + a2; }
    __syncthreads();
    for (int b = tid; b < NB; b += 256)
        gbase[b] = h[b] ? atomicAdd(&bcur[b], h[b]) : 0;
    __syncthreads();
    // rank & stage
    for (int i = tid; i < n; i += 256) {
        int d = dst[e0 + i];
        int s = src[e0 + i];
        int b = d >> CB;
        int p = atomicAdd(&cur[b], 1);
        stage[p] = (unsigned int)s | ((unsigned int)(d & (BUKN - 1)) << 20);
        binOf[p] = (unsigned short)b;
    }
    __syncthreads();
    // coalesced write-out per bucket run
    for (int i = tid; i < n; i += 256) {
        int b = binOf[i];
        pair[gbase[b] + (i - exc[b])] = stage[i];
    }
}

// ---------------------------------------------------------------------------
// Per-bucket CSR build: histogram 128 local bins, scan, emit rowptr/deg/dinv,
// place srcs within the bucket's contiguous 32KB window. 782 WGs.
// ---------------------------------------------------------------------------
__global__ __launch_bounds__(256) void bucket_build_kernel(const unsigned int* __restrict__ pair,
                                                           const int* __restrict__ cofs,
                                                           int* __restrict__ rowptr,
                                                           int* __restrict__ degi,
                                                           float* __restrict__ dinv,
                                                           int* __restrict__ srcs) {
    __shared__ int h[BUKN];
    __shared__ int sc[BUKN];
    __shared__ int cur[BUKN];
    int tid = threadIdx.x;
    int b = blockIdx.x;
    int lo = cofs[b], hi = cofs[b + 1];

    if (tid < BUKN) h[tid] = 0;
    __syncthreads();
    for (int i = lo + tid; i < hi; i += 256)
        atomicAdd(&h[pair[i] >> 20], 1);
    __syncthreads();
    if (tid < BUKN) sc[tid] = h[tid];
    __syncthreads();
    for (int st = 1; st < BUKN; st <<= 1) {
        int add = (tid >= st && tid < BUKN) ? sc[tid - st] : 0;
        __syncthreads();
        if (tid < BUKN) sc[tid] += add;
        __syncthreads();
    }
    if (tid < BUKN) {
        int excl = sc[tid] - h[tid];
        int v = (b << CB) + tid;
        cur[tid] = lo + excl;
        if (v < NN) {
            rowptr[v] = lo + excl;
            degi[v]   = h[tid];
            dinv[v]   = rsqrtf((float)(h[tid] + 1));   // +1 self-loop
        }
    }
    __syncthreads();
    for (int i = lo + tid; i < hi; i += 256) {
        unsigned int pd = pair[i];
        int p = atomicAdd(&cur[pd >> 20], 1);
        srcs[p] = (int)(pd & 0xFFFFFu);
    }
}

// ---------------------------------------------------------------------------
// Layer-1 transform: t1[v,:] = (x[v,:] @ W1) * dinv[v], stored f16
// ---------------------------------------------------------------------------
__global__ __launch_bounds__(256) void gemm1_kernel(const float* __restrict__ x,
                                                    const float* __restrict__ W1,
                                                    const float* __restrict__ dinv,
                                                    __half* __restrict__ t1) {
    __shared__ float W1s[FIN][HD];        // 8 KB
    __shared__ float xs[16][FIN + 1];
    int tid = threadIdx.x;
    int nodeBase = blockIdx.x * 16;

    for (int i = tid; i < FIN * HD; i += 256) W1s[i >> 4][i & 15] = W1[i];
    for (int i = tid; i < 16 * FIN; i += 256) {
        int r = i >> 7, c = i & 127;
        int v = nodeBase + r;
        xs[r][c] = (v < NN) ? x[(long long)v * FIN + c] : 0.0f;
    }
    __syncthreads();

    int r = tid >> 4, j = tid & 15;
    int v = nodeBase + r;
    if (v < NN) {
        float acc = 0.0f;
        #pragma unroll
        for (int k = 0; k < FIN; ++k) acc += xs[r][k] * W1s[k][j];
        t1[v * HD + j] = __float2half(acc * dinv[v]);
    }
}

// ---------------------------------------------------------------------------
// Gather layer 1 (fused ReLU epilogue): wave per node, 8 subgroups x 8 lanes,
// each lane covers 2 features via __half2. t2 = relu(di*(acc+self)+b1)*di (f16).
// ---------------------------------------------------------------------------
__global__ __launch_bounds__(256) void gather_relu_kernel(const int* __restrict__ rowptr,
                                                          const int* __restrict__ degi,
                                                          const int* __restrict__ srcs,
                                                          const __half2* __restrict__ t1,
                                                          const float* __restrict__ dinv,
                                                          const float* __restrict__ b1,
                                                          __half2* __restrict__ t2) {
    int gw = (blockIdx.x * 256 + threadIdx.x) >> 6;   // node = global wave id
    int lane = threadIdx.x & 63;
    int start = rowptr[gw];
    int cnt   = degi[gw];
    int jh  = lane & 7;        // feature pair index
    int sub = lane >> 3;       // 0..7
    float2 acc = {0.0f, 0.0f};
    int e = sub;
    for (; e + 24 < cnt; e += 32) {      // 4-deep MLP, 8 edges per instr
        int s0 = srcs[start + e];
        int s1 = srcs[start + e + 8];
        int s2 = srcs[start + e + 16];
        int s3 = srcs[start + e + 24];
        float2 v0 = __half22float2(t1[s0 * 8 + jh]);
        float2 v1 = __half22float2(t1[s1 * 8 + jh]);
        float2 v2 = __half22float2(t1[s2 * 8 + jh]);
        float2 v3 = __half22float2(t1[s3 * 8 + jh]);
        acc.x += v0.x + v1.x + v2.x + v3.x;
        acc.y += v0.y + v1.y + v2.y + v3.y;
    }
    for (; e < cnt; e += 8) {
        float2 v = __half22float2(t1[srcs[start + e] * 8 + jh]);
        acc.x += v.x; acc.y += v.y;
    }
    acc.x += __shfl_xor(acc.x, 8);  acc.y += __shfl_xor(acc.y, 8);
    acc.x += __shfl_xor(acc.x, 16); acc.y += __shfl_xor(acc.y, 16);
    acc.x += __shfl_xor(acc.x, 32); acc.y += __shfl_xor(acc.y, 32);
    if (sub == 0) {
        float2 self = __half22float2(t1[gw * 8 + jh]);
        float di = dinv[gw];
        float r0 = fmaxf(di * (acc.x + self.x) + b1[2 * jh], 0.0f) * di;
        float r1 = fmaxf(di * (acc.y + self.y) + b1[2 * jh + 1], 0.0f) * di;
        t2[gw * 8 + jh] = __floats2half2_rn(r0, r1);
    }
}

// ---------------------------------------------------------------------------
// Gather layer 2 fused with W2 transform: block = 4 waves = 4 nodes.
// agg2 staged in LDS per wave, then out[v,:] = (di*agg2) @ W2 + b2.
// Grid exact: NN/4 = 25000 blocks, no bounds guards (NN % 4 == 0).
// ---------------------------------------------------------------------------
__global__ __launch_bounds__(256) void gather_gemm2_kernel(const int* __restrict__ rowptr,
                                                           const int* __restrict__ degi,
                                                           const int* __restrict__ srcs,
                                                           const __half2* __restrict__ t2,
                                                           const float* __restrict__ dinv,
                                                           const float* __restrict__ W2,
                                                           const float* __restrict__ b2,
                                                           float* __restrict__ out) {
    __shared__ float W2s[HD][FOUT];   // 4 KB
    __shared__ float aS[4][HD];
    int tid = threadIdx.x;
    int wv = tid >> 6;
    int gw = blockIdx.x * 4 + wv;
    int lane = tid & 63;
    int jh  = lane & 7;
    int sub = lane >> 3;

    for (int i = tid; i < HD * FOUT; i += 256) W2s[i >> 6][i & 63] = W2[i];

    int start = rowptr[gw];
    int cnt   = degi[gw];
    float2 acc = {0.0f, 0.0f};
    int e = sub;
    for (; e + 24 < cnt; e += 32) {
        int s0 = srcs[start + e];
        int s1 = srcs[start + e + 8];
        int s2 = srcs[start + e + 16];
        int s3 = srcs[start + e + 24];
        float2 v0 = __half22float2(t2[s0 * 8 + jh]);
        float2 v1 = __half22float2(t2[s1 * 8 + jh]);
        float2 v2 = __half22float2(t2[s2 * 8 + jh]);
        float2 v3 = __half22float2(t2[s3 * 8 + jh]);
        acc.x += v0.x + v1.x + v2.x + v3.x;
        acc.y += v0.y + v1.y + v2.y + v3.y;
    }
    for (; e < cnt; e += 8) {
        float2 v = __half22float2(t2[srcs[start + e] * 8 + jh]);
        acc.x += v.x; acc.y += v.y;
    }
    acc.x += __shfl_xor(acc.x, 8);  acc.y += __shfl_xor(acc.y, 8);
    acc.x += __shfl_xor(acc.x, 16); acc.y += __shfl_xor(acc.y, 16);
    acc.x += __shfl_xor(acc.x, 32); acc.y += __shfl_xor(acc.y, 32);
    if (sub == 0) {
        float2 self = __half22float2(t2[gw * 8 + jh]);
        float di = dinv[gw];
        aS[wv][2 * jh]     = di * (acc.x + self.x);
        aS[wv][2 * jh + 1] = di * (acc.y + self.y);
    }
    __syncthreads();

    int jo = lane;
    float facc = b2[jo];
    #pragma unroll
    for (int k = 0; k < HD; ++k) facc += aS[wv][k] * W2s[k][jo];
    out[(long long)gw * FOUT + jo] = facc;
}

// ---------------------------------------------------------------------------
extern "C" void kernel_launch(void* const* d_in, const int* in_sizes, int n_in,
                              void* d_out, int out_size, void* d_ws, size_t ws_size,
                              hipStream_t stream) {
    const float* x  = (const float*)d_in[0];
    const int*   ei = (const int*)d_in[1];      // [2, E] row-major
    const float* W1 = (const float*)d_in[2];
    const float* b1 = (const float*)d_in[3];
    const float* W2 = (const float*)d_in[4];
    const float* b2 = (const float*)d_in[5];
    float* out = (float*)d_out;

    const int* src = ei;
    const int* dst = ei + EE;

    // workspace layout (~60 MB)
    int* wsI    = (int*)d_ws;
    int* chist  = wsI;                     // NBPAD
    int* cofs   = chist + NBPAD;           // NBPAD+1 (pad to NBPAD+32)
    int* bcur   = cofs + NBPAD + 32;       // NBPAD
    int* rowptr = bcur + NBPAD;            // N
    int* degi   = rowptr + NN;             // N
    float* dinv = (float*)(degi + NN);     // N
    unsigned int* pair = (unsigned int*)(dinv + NN);  // E  (25.6 MB)
    int* srcs   = (int*)(pair + EE);       // E  (25.6 MB)
    __half* t1  = (__half*)(srcs + EE);    // N*HD f16 (3.2 MB)
    __half* t2  = t1 + NN * HD;            // N*HD f16 (3.2 MB)

    // bucket sort by dst>>7 (packed dstLow|src) + per-bucket CSR
    zero_chist_kernel<<<(NBPAD + 255) / 256, 256, 0, stream>>>(chist);
    coarse_hist_kernel<<<1024, 256, 0, stream>>>(dst, chist);
    scan_coarse_kernel<<<1, 256, 0, stream>>>(chist, cofs, bcur);
    coarse_scatter_kernel<<<NCHUNK, 256, 0, stream>>>(src, dst, bcur, pair);
    bucket_build_kernel<<<NBUK, 256, 0, stream>>>(pair, cofs, rowptr, degi, dinv, srcs);

    // layer 1: transform (f16 table), gather with fused epilogue -> t2 (f16)
    gemm1_kernel<<<(NN + 15) / 16, 256, 0, stream>>>(x, W1, dinv, t1);
    gather_relu_kernel<<<NN / 4, 256, 0, stream>>>(rowptr, degi, srcs,
                                                   (const __half2*)t1, dinv, b1,
                                                   (__half2*)t2);
    // layer 2: gather fused with dinv-scale + W2 transform
    gather_gemm2_kernel<<<NN / 4, 256, 0, stream>>>(rowptr, degi, srcs,
                                                    (const __half2*)t2, dinv, W2, b2, out);
}

// Round 9
// 418.750 us; speedup vs baseline: 3.8736x; 1.0576x over previous
//
#include <hip/hip_runtime.h>
#include <hip/hip_fp16.h>

// Problem constants (from reference)
constexpr int NN   = 100000;    // nodes
constexpr int EE   = 6400000;   // directed edges
constexpr int FIN  = 128;
constexpr int HD   = 16;
constexpr int FOUT = 64;

// Bucketing parameters: coarse bucket = dst >> 9 (196 buckets, binOf fits u8)
constexpr int CB     = 9;
constexpr int BUKN   = 1 << CB;                    // 512 nodes per bucket
constexpr int NBUK   = (NN + BUKN - 1) >> CB;      // 196 buckets
constexpr int CHUNK  = 8192;                       // edges per WG in coarse scatter
constexpr int NCHUNK = (EE + CHUNK - 1) / CHUNK;   // 782

// ---------------------------------------------------------------------------
__global__ __launch_bounds__(256) void zero_chist_kernel(int* __restrict__ chist) {
    chist[threadIdx.x] = 0;     // 256 entries (196 used)
}

// Coarse histogram over dst>>CB, LDS-staged
__global__ __launch_bounds__(256) void coarse_hist_kernel(const int* __restrict__ dst,
                                                          int* __restrict__ chist) {
    __shared__ int h[256];
    int tid = threadIdx.x;
    h[tid] = 0;
    __syncthreads();
    int stride = gridDim.x * 256;
    for (int i = blockIdx.x * 256 + tid; i < EE / 4; i += stride) {
        int4 d4 = reinterpret_cast<const int4*>(dst)[i];
        atomicAdd(&h[d4.x >> CB], 1);
        atomicAdd(&h[d4.y >> CB], 1);
        atomicAdd(&h[d4.z >> CB], 1);
        atomicAdd(&h[d4.w >> CB], 1);
    }
    __syncthreads();
    if (h[tid]) atomicAdd(&chist[tid], h[tid]);
}

// Exclusive scan of 256 coarse bins -> cofs[257]; bcur = working cursors
__global__ __launch_bounds__(256) void scan_coarse_kernel(const int* __restrict__ chist,
                                                          int* __restrict__ cofs,
                                                          int* __restrict__ bcur) {
    __shared__ int s[256];
    int tid = threadIdx.x;
    int val = chist[tid];
    s[tid] = val;
    __syncthreads();
    for (int st = 1; st < 256; st <<= 1) {
        int add = (tid >= st) ? s[tid - st] : 0;
        __syncthreads();
        s[tid] += add;
        __syncthreads();
    }
    int excl = s[tid] - val;
    cofs[tid] = excl;
    bcur[tid] = excl;
    if (tid == 255) cofs[256] = s[255];
}

// Coarse scatter: rank chunk's edges by bucket in LDS, claim global bases,
// write packed (dstLow<<20 | src) u32s in long coalesced per-bucket runs.
// CHUNK=8192, 196 bins -> avg run 42 edges = 167B (full-line writes).
__global__ __launch_bounds__(256) void coarse_scatter_kernel(const int* __restrict__ src,
                                                             const int* __restrict__ dst,
                                                             int* __restrict__ bcur,
                                                             unsigned int* __restrict__ pair) {
    __shared__ int h[256];
    __shared__ int exc[256];
    __shared__ int cur[256];
    __shared__ int gbase[256];
    __shared__ unsigned int stage[CHUNK];        // 32 KB
    __shared__ unsigned char binOf[CHUNK];       // 8 KB
    int tid = threadIdx.x;
    int e0 = blockIdx.x * CHUNK;
    int n = min(CHUNK, EE - e0);

    h[tid] = 0;
    __syncthreads();
    for (int i = tid; i < n; i += 256) atomicAdd(&h[dst[e0 + i] >> CB], 1);
    __syncthreads();
    // exclusive scan of h -> exc (one bin per thread)
    {
        int val = h[tid];
        exc[tid] = val;
        __syncthreads();
        for (int st = 1; st < 256; st <<= 1) {
            int add = (tid >= st) ? exc[tid - st] : 0;
            __syncthreads();
            exc[tid] += add;
            __syncthreads();
        }
        exc[tid] -= val;
    }
    cur[tid] = exc[tid];
    gbase[tid] = h[tid] ? atomicAdd(&bcur[tid], h[tid]) : 0;
    __syncthreads();
    // rank & stage
    for (int i = tid; i < n; i += 256) {
        int d = dst[e0 + i];
        int s = src[e0 + i];
        int b = d >> CB;
        int p = atomicAdd(&cur[b], 1);
        stage[p] = (unsigned int)s | ((unsigned int)(d & (BUKN - 1)) << 20);
        binOf[p] = (unsigned char)b;
    }
    __syncthreads();
    // coalesced write-out per bucket run
    for (int i = tid; i < n; i += 256) {
        int b = binOf[i];
        pair[gbase[b] + (i - exc[b])] = stage[i];
    }
}

// ---------------------------------------------------------------------------
// Per-bucket CSR build, 1024-thread WGs (fixes R4's 7%-occupancy version):
// histogram 512 local bins, scan, emit rowptr/deg/dinv, place srcs within the
// bucket's contiguous 130KB (single-XCD-L2) window. 196 WGs x 16 waves.
// ---------------------------------------------------------------------------
__global__ __launch_bounds__(1024) void bucket_build_kernel(const unsigned int* __restrict__ pair,
                                                            const int* __restrict__ cofs,
                                                            int* __restrict__ rowptr,
                                                            int* __restrict__ degi,
                                                            float* __restrict__ dinv,
                                                            int* __restrict__ srcs) {
    __shared__ int h[BUKN];
    __shared__ int sc[BUKN];
    __shared__ int cur[BUKN];
    int tid = threadIdx.x;
    int b = blockIdx.x;
    int lo = cofs[b], hi = cofs[b + 1];

    if (tid < BUKN) h[tid] = 0;
    __syncthreads();
    for (int i = lo + tid; i < hi; i += 1024)
        atomicAdd(&h[(pair[i] >> 20) & (BUKN - 1)], 1);
    __syncthreads();
    if (tid < BUKN) sc[tid] = h[tid];
    __syncthreads();
    for (int st = 1; st < BUKN; st <<= 1) {
        int add = (tid >= st && tid < BUKN) ? sc[tid - st] : 0;
        __syncthreads();
        if (tid < BUKN) sc[tid] += add;
        __syncthreads();
    }
    if (tid < BUKN) {
        int excl = sc[tid] - h[tid];
        int v = (b << CB) + tid;
        cur[tid] = lo + excl;
        if (v < NN) {
            rowptr[v] = lo + excl;
            degi[v]   = h[tid];
            dinv[v]   = rsqrtf((float)(h[tid] + 1));   // +1 self-loop
        }
    }
    __syncthreads();
    for (int i = lo + tid; i < hi; i += 1024) {
        unsigned int pd = pair[i];
        int p = atomicAdd(&cur[(pd >> 20) & (BUKN - 1)], 1);
        srcs[p] = (int)(pd & 0xFFFFFu);
    }
}

// ---------------------------------------------------------------------------
// Layer-1 transform: t1[v,:] = (x[v,:] @ W1) * dinv[v], stored f16
// ---------------------------------------------------------------------------
__global__ __launch_bounds__(256) void gemm1_kernel(const float* __restrict__ x,
                                                    const float* __restrict__ W1,
                                                    const float* __restrict__ dinv,
                                                    __half* __restrict__ t1) {
    __shared__ float W1s[FIN][HD];        // 8 KB
    __shared__ float xs[16][FIN + 1];
    int tid = threadIdx.x;
    int nodeBase = blockIdx.x * 16;

    for (int i = tid; i < FIN * HD; i += 256) W1s[i >> 4][i & 15] = W1[i];
    for (int i = tid; i < 16 * FIN; i += 256) {
        int r = i >> 7, c = i & 127;
        int v = nodeBase + r;
        xs[r][c] = (v < NN) ? x[(long long)v * FIN + c] : 0.0f;
    }
    __syncthreads();

    int r = tid >> 4, j = tid & 15;
    int v = nodeBase + r;
    if (v < NN) {
        float acc = 0.0f;
        #pragma unroll
        for (int k = 0; k < FIN; ++k) acc += xs[r][k] * W1s[k][j];
        t1[v * HD + j] = __float2half(acc * dinv[v]);
    }
}

// ---------------------------------------------------------------------------
// Gather layer 1 (fused ReLU epilogue): wave per node, 8 subgroups x 8 lanes,
// each lane covers 2 features via __half2. t2 = relu(di*(acc+self)+b1)*di (f16).
// ---------------------------------------------------------------------------
__global__ __launch_bounds__(256) void gather_relu_kernel(const int* __restrict__ rowptr,
                                                          const int* __restrict__ degi,
                                                          const int* __restrict__ srcs,
                                                          const __half2* __restrict__ t1,
                                                          const float* __restrict__ dinv,
                                                          const float* __restrict__ b1,
                                                          __half2* __restrict__ t2) {
    int gw = (blockIdx.x * 256 + threadIdx.x) >> 6;   // node = global wave id
    int lane = threadIdx.x & 63;
    int start = rowptr[gw];
    int cnt   = degi[gw];
    int jh  = lane & 7;        // feature pair index
    int sub = lane >> 3;       // 0..7
    float2 acc = {0.0f, 0.0f};
    int e = sub;
    for (; e + 24 < cnt; e += 32) {      // 4-deep MLP, 8 edges per instr
        int s0 = srcs[start + e];
        int s1 = srcs[start + e + 8];
        int s2 = srcs[start + e + 16];
        int s3 = srcs[start + e + 24];
        float2 v0 = __half22float2(t1[s0 * 8 + jh]);
        float2 v1 = __half22float2(t1[s1 * 8 + jh]);
        float2 v2 = __half22float2(t1[s2 * 8 + jh]);
        float2 v3 = __half22float2(t1[s3 * 8 + jh]);
        acc.x += v0.x + v1.x + v2.x + v3.x;
        acc.y += v0.y + v1.y + v2.y + v3.y;
    }
    for (; e < cnt; e += 8) {
        float2 v = __half22float2(t1[srcs[start + e] * 8 + jh]);
        acc.x += v.x; acc.y += v.y;
    }
    acc.x += __shfl_xor(acc.x, 8);  acc.y += __shfl_xor(acc.y, 8);
    acc.x += __shfl_xor(acc.x, 16); acc.y += __shfl_xor(acc.y, 16);
    acc.x += __shfl_xor(acc.x, 32); acc.y += __shfl_xor(acc.y, 32);
    if (sub == 0) {
        float2 self = __half22float2(t1[gw * 8 + jh]);
        float di = dinv[gw];
        float r0 = fmaxf(di * (acc.x + self.x) + b1[2 * jh], 0.0f) * di;
        float r1 = fmaxf(di * (acc.y + self.y) + b1[2 * jh + 1], 0.0f) * di;
        t2[gw * 8 + jh] = __floats2half2_rn(r0, r1);
    }
}

// ---------------------------------------------------------------------------
// Gather layer 2 fused with W2 transform: block = 4 waves = 4 nodes.
// agg2 staged in LDS per wave, then out[v,:] = (di*agg2) @ W2 + b2.
// Grid exact: NN/4 = 25000 blocks (NN % 4 == 0).
// ---------------------------------------------------------------------------
__global__ __launch_bounds__(256) void gather_gemm2_kernel(const int* __restrict__ rowptr,
                                                           const int* __restrict__ degi,
                                                           const int* __restrict__ srcs,
                                                           const __half2* __restrict__ t2,
                                                           const float* __restrict__ dinv,
                                                           const float* __restrict__ W2,
                                                           const float* __restrict__ b2,
                                                           float* __restrict__ out) {
    __shared__ float W2s[HD][FOUT];   // 4 KB
    __shared__ float aS[4][HD];
    int tid = threadIdx.x;
    int wv = tid >> 6;
    int gw = blockIdx.x * 4 + wv;
    int lane = tid & 63;
    int jh  = lane & 7;
    int sub = lane >> 3;

    for (int i = tid; i < HD * FOUT; i += 256) W2s[i >> 6][i & 63] = W2[i];

    int start = rowptr[gw];
    int cnt   = degi[gw];
    float2 acc = {0.0f, 0.0f};
    int e = sub;
    for (; e + 24 < cnt; e += 32) {
        int s0 = srcs[start + e];
        int s1 = srcs[start + e + 8];
        int s2 = srcs[start + e + 16];
        int s3 = srcs[start + e + 24];
        float2 v0 = __half22float2(t2[s0 * 8 + jh]);
        float2 v1 = __half22float2(t2[s1 * 8 + jh]);
        float2 v2 = __half22float2(t2[s2 * 8 + jh]);
        float2 v3 = __half22float2(t2[s3 * 8 + jh]);
        acc.x += v0.x + v1.x + v2.x + v3.x;
        acc.y += v0.y + v1.y + v2.y + v3.y;
    }
    for (; e < cnt; e += 8) {
        float2 v = __half22float2(t2[srcs[start + e] * 8 + jh]);
        acc.x += v.x; acc.y += v.y;
    }
    acc.x += __shfl_xor(acc.x, 8);  acc.y += __shfl_xor(acc.y, 8);
    acc.x += __shfl_xor(acc.x, 16); acc.y += __shfl_xor(acc.y, 16);
    acc.x += __shfl_xor(acc.x, 32); acc.y += __shfl_xor(acc.y, 32);
    if (sub == 0) {
        float2 self = __half22float2(t2[gw * 8 + jh]);
        float di = dinv[gw];
        aS[wv][2 * jh]     = di * (acc.x + self.x);
        aS[wv][2 * jh + 1] = di * (acc.y + self.y);
    }
    __syncthreads();

    int jo = lane;
    float facc = b2[jo];
    #pragma unroll
    for (int k = 0; k < HD; ++k) facc += aS[wv][k] * W2s[k][jo];
    out[(long long)gw * FOUT + jo] = facc;
}

// ---------------------------------------------------------------------------
extern "C" void kernel_launch(void* const* d_in, const int* in_sizes, int n_in,
                              void* d_out, int out_size, void* d_ws, size_t ws_size,
                              hipStream_t stream) {
    const float* x  = (const float*)d_in[0];
    const int*   ei = (const int*)d_in[1];      // [2, E] row-major
    const float* W1 = (const float*)d_in[2];
    const float* b1 = (const float*)d_in[3];
    const float* W2 = (const float*)d_in[4];
    const float* b2 = (const float*)d_in[5];
    float* out = (float*)d_out;

    const int* src = ei;
    const int* dst = ei + EE;

    // workspace layout (~58 MB)
    int* wsI    = (int*)d_ws;
    int* chist  = wsI;                     // 256
    int* cofs   = chist + 256;             // 257 (pad 288)
    int* bcur   = cofs + 288;              // 256
    int* rowptr = bcur + 256;              // N
    int* degi   = rowptr + NN;             // N
    float* dinv = (float*)(degi + NN);     // N
    unsigned int* pair = (unsigned int*)(dinv + NN);  // E  (25.6 MB)
    int* srcs   = (int*)(pair + EE);       // E  (25.6 MB)
    __half* t1  = (__half*)(srcs + EE);    // N*HD f16 (3.2 MB)
    __half* t2  = t1 + NN * HD;            // N*HD f16 (3.2 MB)

    // bucket sort by dst>>9 (packed dstLow|src) + per-bucket CSR
    zero_chist_kernel<<<1, 256, 0, stream>>>(chist);
    coarse_hist_kernel<<<1024, 256, 0, stream>>>(dst, chist);
    scan_coarse_kernel<<<1, 256, 0, stream>>>(chist, cofs, bcur);
    coarse_scatter_kernel<<<NCHUNK, 256, 0, stream>>>(src, dst, bcur, pair);
    bucket_build_kernel<<<NBUK, 1024, 0, stream>>>(pair, cofs, rowptr, degi, dinv, srcs);

    // layer 1: transform (f16 table), gather with fused epilogue -> t2 (f16)
    gemm1_kernel<<<(NN + 15) / 16, 256, 0, stream>>>(x, W1, dinv, t1);
    gather_relu_kernel<<<NN / 4, 256, 0, stream>>>(rowptr, degi, srcs,
                                                   (const __half2*)t1, dinv, b1,
                                                   (__half2*)t2);
    // layer 2: gather fused with dinv-scale + W2 transform
    gather_gemm2_kernel<<<NN / 4, 256, 0, stream>>>(rowptr, degi, srcs,
                                                    (const __half2*)t2, dinv, W2, b2, out);
}

// Round 10
// 353.464 us; speedup vs baseline: 4.5891x; 1.1847x over previous
//
#include <hip/hip_runtime.h>
#include <hip/hip_fp16.h>

// Problem constants (from reference)
constexpr int NN   = 100000;    // nodes
constexpr int EE   = 6400000;   // directed edges
constexpr int FIN  = 128;
constexpr int HD   = 16;
constexpr int FOUT = 64;

// Bucketing parameters: coarse bucket = dst >> 9 (196 buckets, binOf fits u8)
constexpr int CB     = 9;
constexpr int BUKN   = 1 << CB;                    // 512 nodes per bucket
constexpr int NBUK   = (NN + BUKN - 1) >> CB;      // 196 buckets
constexpr int CHUNK  = 8192;                       // edges per WG in scatter
constexpr int NCHUNK = (EE + CHUNK - 1) / CHUNK;   // 782

// ---------------------------------------------------------------------------
// Pass A: per-chunk 196-bin histogram -> histG[c][256]  (int4 loads)
// ---------------------------------------------------------------------------
__global__ __launch_bounds__(256) void chunk_hist_kernel(const int* __restrict__ dst,
                                                         int* __restrict__ histG) {
    __shared__ int h[256];
    int tid = threadIdx.x;
    int c = blockIdx.x;
    int e0 = c * CHUNK;
    int n = min(CHUNK, EE - e0);
    h[tid] = 0;
    __syncthreads();
    const int4* dst4 = reinterpret_cast<const int4*>(dst + e0);
    int n4 = n >> 2;                       // EE%4==0, CHUNK%4==0
    for (int i = tid; i < n4; i += 256) {
        int4 d = dst4[i];
        atomicAdd(&h[d.x >> CB], 1);
        atomicAdd(&h[d.y >> CB], 1);
        atomicAdd(&h[d.z >> CB], 1);
        atomicAdd(&h[d.w >> CB], 1);
    }
    __syncthreads();
    histG[c * 256 + tid] = h[tid];         // b>=NBUK columns are zero
}

// ---------------------------------------------------------------------------
// Pass B1: per-bucket column prefix over chunks: offsL[c][b] = sum_{c'<c} hist,
// totG[b] = column total. Grid = 256 (all columns, so totG fully defined).
// ---------------------------------------------------------------------------
__global__ __launch_bounds__(256) void colscan_kernel(const int* __restrict__ histG,
                                                      int* __restrict__ offsL,
                                                      int* __restrict__ totG) {
    __shared__ int ps[256];
    int t = threadIdx.x;
    int b = blockIdx.x;
    int c0 = 4 * t;
    int v0 = (c0     < NCHUNK) ? histG[(c0    ) * 256 + b] : 0;
    int v1 = (c0 + 1 < NCHUNK) ? histG[(c0 + 1) * 256 + b] : 0;
    int v2 = (c0 + 2 < NCHUNK) ? histG[(c0 + 2) * 256 + b] : 0;
    int v3 = (c0 + 3 < NCHUNK) ? histG[(c0 + 3) * 256 + b] : 0;
    int tot = v0 + v1 + v2 + v3;
    ps[t] = tot;
    __syncthreads();
    for (int st = 1; st < 256; st <<= 1) {
        int add = (t >= st) ? ps[t - st] : 0;
        __syncthreads();
        ps[t] += add;
        __syncthreads();
    }
    int base = ps[t] - tot;
    if (c0     < NCHUNK) offsL[(c0    ) * 256 + b] = base;
    if (c0 + 1 < NCHUNK) offsL[(c0 + 1) * 256 + b] = base + v0;
    if (c0 + 2 < NCHUNK) offsL[(c0 + 2) * 256 + b] = base + v0 + v1;
    if (c0 + 3 < NCHUNK) offsL[(c0 + 3) * 256 + b] = base + v0 + v1 + v2;
    if (t == 255) totG[b] = ps[255];
}

// ---------------------------------------------------------------------------
// Pass B2: exclusive scan of totG -> cofs[257]
// ---------------------------------------------------------------------------
__global__ __launch_bounds__(256) void scan_coarse_kernel(const int* __restrict__ totG,
                                                          int* __restrict__ cofs) {
    __shared__ int s[256];
    int tid = threadIdx.x;
    int val = totG[tid];
    s[tid] = val;
    __syncthreads();
    for (int st = 1; st < 256; st <<= 1) {
        int add = (tid >= st) ? s[tid - st] : 0;
        __syncthreads();
        s[tid] += add;
        __syncthreads();
    }
    cofs[tid] = s[tid] - val;
    if (tid == 255) cofs[256] = s[255];
}

// ---------------------------------------------------------------------------
// Pass C: no-claim scatter. Load own hist row + precomputed bases, rank via
// one LDS atomic per edge, stage sorted in LDS, coalesced per-run writeout.
// 512 threads (8 waves), LDS ~45KB -> 3 WG/CU = 24 waves/CU.
// ---------------------------------------------------------------------------
__global__ __launch_bounds__(512) void coarse_scatter_kernel(const int* __restrict__ src,
                                                             const int* __restrict__ dst,
                                                             const int* __restrict__ histG,
                                                             const int* __restrict__ offsL,
                                                             const int* __restrict__ cofs,
                                                             unsigned int* __restrict__ pair) {
    __shared__ int exc[256];
    __shared__ int cur[256];
    __shared__ int gbase[256];
    __shared__ int ps[256];
    __shared__ unsigned int stage[CHUNK];        // 32 KB
    __shared__ unsigned char binOf[CHUNK];       // 8 KB
    int tid = threadIdx.x;
    int c = blockIdx.x;
    int e0 = c * CHUNK;
    int n = min(CHUNK, EE - e0);

    int val = 0;
    if (tid < 256) {
        val = histG[c * 256 + tid];
        ps[tid] = val;
        gbase[tid] = cofs[tid] + offsL[c * 256 + tid];
    }
    __syncthreads();
    for (int st = 1; st < 256; st <<= 1) {
        int add = (tid >= st && tid < 256) ? ps[tid - st] : 0;
        __syncthreads();
        if (tid < 256) ps[tid] += add;
        __syncthreads();
    }
    if (tid < 256) { exc[tid] = ps[tid] - val; cur[tid] = ps[tid] - val; }
    __syncthreads();

    // rank & stage (int4 loads; EE%4==0 so n%4==0)
    const int4* dst4 = reinterpret_cast<const int4*>(dst + e0);
    const int4* src4 = reinterpret_cast<const int4*>(src + e0);
    int n4 = n >> 2;
    for (int i = tid; i < n4; i += 512) {
        int4 d = dst4[i];
        int4 s = src4[i];
        int b0 = d.x >> CB, b1 = d.y >> CB, b2 = d.z >> CB, b3 = d.w >> CB;
        int p0 = atomicAdd(&cur[b0], 1);
        int p1 = atomicAdd(&cur[b1], 1);
        int p2 = atomicAdd(&cur[b2], 1);
        int p3 = atomicAdd(&cur[b3], 1);
        stage[p0] = (unsigned int)s.x | ((unsigned int)(d.x & (BUKN - 1)) << 20);
        stage[p1] = (unsigned int)s.y | ((unsigned int)(d.y & (BUKN - 1)) << 20);
        stage[p2] = (unsigned int)s.z | ((unsigned int)(d.z & (BUKN - 1)) << 20);
        stage[p3] = (unsigned int)s.w | ((unsigned int)(d.w & (BUKN - 1)) << 20);
        binOf[p0] = (unsigned char)b0;
        binOf[p1] = (unsigned char)b1;
        binOf[p2] = (unsigned char)b2;
        binOf[p3] = (unsigned char)b3;
    }
    __syncthreads();
    // coalesced write-out per bucket run
    for (int i = tid; i < n; i += 512) {
        int b = binOf[i];
        pair[gbase[b] + (i - exc[b])] = stage[i];
    }
}

// ---------------------------------------------------------------------------
// Per-bucket CSR build, 1024-thread WGs: histogram 512 local bins, scan, emit
// rowptr/deg/dinv, place srcs within the bucket's contiguous 130KB window.
// ---------------------------------------------------------------------------
__global__ __launch_bounds__(1024) void bucket_build_kernel(const unsigned int* __restrict__ pair,
                                                            const int* __restrict__ cofs,
                                                            int* __restrict__ rowptr,
                                                            int* __restrict__ degi,
                                                            float* __restrict__ dinv,
                                                            int* __restrict__ srcs) {
    __shared__ int h[BUKN];
    __shared__ int sc[BUKN];
    __shared__ int cur[BUKN];
    int tid = threadIdx.x;
    int b = blockIdx.x;
    int lo = cofs[b], hi = cofs[b + 1];

    if (tid < BUKN) h[tid] = 0;
    __syncthreads();
    for (int i = lo + tid; i < hi; i += 1024)
        atomicAdd(&h[(pair[i] >> 20) & (BUKN - 1)], 1);
    __syncthreads();
    if (tid < BUKN) sc[tid] = h[tid];
    __syncthreads();
    for (int st = 1; st < BUKN; st <<= 1) {
        int add = (tid >= st && tid < BUKN) ? sc[tid - st] : 0;
        __syncthreads();
        if (tid < BUKN) sc[tid] += add;
        __syncthreads();
    }
    if (tid < BUKN) {
        int excl = sc[tid] - h[tid];
        int v = (b << CB) + tid;
        cur[tid] = lo + excl;
        if (v < NN) {
            rowptr[v] = lo + excl;
            degi[v]   = h[tid];
            dinv[v]   = rsqrtf((float)(h[tid] + 1));   // +1 self-loop
        }
    }
    __syncthreads();
    for (int i = lo + tid; i < hi; i += 1024) {
        unsigned int pd = pair[i];
        int p = atomicAdd(&cur[(pd >> 20) & (BUKN - 1)], 1);
        srcs[p] = (int)(pd & 0xFFFFFu);
    }
}

// ---------------------------------------------------------------------------
// Layer-1 transform: t1[v,:] = (x[v,:] @ W1) * dinv[v], stored f16
// ---------------------------------------------------------------------------
__global__ __launch_bounds__(256) void gemm1_kernel(const float* __restrict__ x,
                                                    const float* __restrict__ W1,
                                                    const float* __restrict__ dinv,
                                                    __half* __restrict__ t1) {
    __shared__ float W1s[FIN][HD];        // 8 KB
    __shared__ float xs[16][FIN + 1];
    int tid = threadIdx.x;
    int nodeBase = blockIdx.x * 16;

    for (int i = tid; i < FIN * HD; i += 256) W1s[i >> 4][i & 15] = W1[i];
    for (int i = tid; i < 16 * FIN; i += 256) {
        int r = i >> 7, c = i & 127;
        int v = nodeBase + r;
        xs[r][c] = (v < NN) ? x[(long long)v * FIN + c] : 0.0f;
    }
    __syncthreads();

    int r = tid >> 4, j = tid & 15;
    int v = nodeBase + r;
    if (v < NN) {
        float acc = 0.0f;
        #pragma unroll
        for (int k = 0; k < FIN; ++k) acc += xs[r][k] * W1s[k][j];
        t1[v * HD + j] = __float2half(acc * dinv[v]);
    }
}

// ---------------------------------------------------------------------------
// Gather layer 1 (fused ReLU epilogue): wave per node, 8 subgroups x 8 lanes,
// each lane covers 2 features via __half2. t2 = relu(di*(acc+self)+b1)*di (f16).
// ---------------------------------------------------------------------------
__global__ __launch_bounds__(256) void gather_relu_kernel(const int* __restrict__ rowptr,
                                                          const int* __restrict__ degi,
                                                          const int* __restrict__ srcs,
                                                          const __half2* __restrict__ t1,
                                                          const float* __restrict__ dinv,
                                                          const float* __restrict__ b1,
                                                          __half2* __restrict__ t2) {
    int gw = (blockIdx.x * 256 + threadIdx.x) >> 6;   // node = global wave id
    int lane = threadIdx.x & 63;
    int start = rowptr[gw];
    int cnt   = degi[gw];
    int jh  = lane & 7;        // feature pair index
    int sub = lane >> 3;       // 0..7
    float2 acc = {0.0f, 0.0f};
    int e = sub;
    for (; e + 24 < cnt; e += 32) {      // 4-deep MLP, 8 edges per instr
        int s0 = srcs[start + e];
        int s1 = srcs[start + e + 8];
        int s2 = srcs[start + e + 16];
        int s3 = srcs[start + e + 24];
        float2 v0 = __half22float2(t1[s0 * 8 + jh]);
        float2 v1 = __half22float2(t1[s1 * 8 + jh]);
        float2 v2 = __half22float2(t1[s2 * 8 + jh]);
        float2 v3 = __half22float2(t1[s3 * 8 + jh]);
        acc.x += v0.x + v1.x + v2.x + v3.x;
        acc.y += v0.y + v1.y + v2.y + v3.y;
    }
    for (; e < cnt; e += 8) {
        float2 v = __half22float2(t1[srcs[start + e] * 8 + jh]);
        acc.x += v.x; acc.y += v.y;
    }
    acc.x += __shfl_xor(acc.x, 8);  acc.y += __shfl_xor(acc.y, 8);
    acc.x += __shfl_xor(acc.x, 16); acc.y += __shfl_xor(acc.y, 16);
    acc.x += __shfl_xor(acc.x, 32); acc.y += __shfl_xor(acc.y, 32);
    if (sub == 0) {
        float2 self = __half22float2(t1[gw * 8 + jh]);
        float di = dinv[gw];
        float r0 = fmaxf(di * (acc.x + self.x) + b1[2 * jh], 0.0f) * di;
        float r1 = fmaxf(di * (acc.y + self.y) + b1[2 * jh + 1], 0.0f) * di;
        t2[gw * 8 + jh] = __floats2half2_rn(r0, r1);
    }
}

// ---------------------------------------------------------------------------
// Gather layer 2 fused with W2 transform: block = 4 waves = 4 nodes.
// ---------------------------------------------------------------------------
__global__ __launch_bounds__(256) void gather_gemm2_kernel(const int* __restrict__ rowptr,
                                                           const int* __restrict__ degi,
                                                           const int* __restrict__ srcs,
                                                           const __half2* __restrict__ t2,
                                                           const float* __restrict__ dinv,
                                                           const float* __restrict__ W2,
                                                           const float* __restrict__ b2,
                                                           float* __restrict__ out) {
    __shared__ float W2s[HD][FOUT];   // 4 KB
    __shared__ float aS[4][HD];
    int tid = threadIdx.x;
    int wv = tid >> 6;
    int gw = blockIdx.x * 4 + wv;
    int lane = tid & 63;
    int jh  = lane & 7;
    int sub = lane >> 3;

    for (int i = tid; i < HD * FOUT; i += 256) W2s[i >> 6][i & 63] = W2[i];

    int start = rowptr[gw];
    int cnt   = degi[gw];
    float2 acc = {0.0f, 0.0f};
    int e = sub;
    for (; e + 24 < cnt; e += 32) {
        int s0 = srcs[start + e];
        int s1 = srcs[start + e + 8];
        int s2 = srcs[start + e + 16];
        int s3 = srcs[start + e + 24];
        float2 v0 = __half22float2(t2[s0 * 8 + jh]);
        float2 v1 = __half22float2(t2[s1 * 8 + jh]);
        float2 v2 = __half22float2(t2[s2 * 8 + jh]);
        float2 v3 = __half22float2(t2[s3 * 8 + jh]);
        acc.x += v0.x + v1.x + v2.x + v3.x;
        acc.y += v0.y + v1.y + v2.y + v3.y;
    }
    for (; e < cnt; e += 8) {
        float2 v = __half22float2(t2[srcs[start + e] * 8 + jh]);
        acc.x += v.x; acc.y += v.y;
    }
    acc.x += __shfl_xor(acc.x, 8);  acc.y += __shfl_xor(acc.y, 8);
    acc.x += __shfl_xor(acc.x, 16); acc.y += __shfl_xor(acc.y, 16);
    acc.x += __shfl_xor(acc.x, 32); acc.y += __shfl_xor(acc.y, 32);
    if (sub == 0) {
        float2 self = __half22float2(t2[gw * 8 + jh]);
        float di = dinv[gw];
        aS[wv][2 * jh]     = di * (acc.x + self.x);
        aS[wv][2 * jh + 1] = di * (acc.y + self.y);
    }
    __syncthreads();

    int jo = lane;
    float facc = b2[jo];
    #pragma unroll
    for (int k = 0; k < HD; ++k) facc += aS[wv][k] * W2s[k][jo];
    out[(long long)gw * FOUT + jo] = facc;
}

// ---------------------------------------------------------------------------
extern "C" void kernel_launch(void* const* d_in, const int* in_sizes, int n_in,
                              void* d_out, int out_size, void* d_ws, size_t ws_size,
                              hipStream_t stream) {
    const float* x  = (const float*)d_in[0];
    const int*   ei = (const int*)d_in[1];      // [2, E] row-major
    const float* W1 = (const float*)d_in[2];
    const float* b1 = (const float*)d_in[3];
    const float* W2 = (const float*)d_in[4];
    const float* b2 = (const float*)d_in[5];
    float* out = (float*)d_out;

    const int* src = ei;
    const int* dst = ei + EE;

    // workspace layout (~60 MB)
    int* wsI    = (int*)d_ws;
    int* histG  = wsI;                     // NCHUNK*256 (800 KB)
    int* offsL  = histG + NCHUNK * 256;    // NCHUNK*256 (800 KB)
    int* totG   = offsL + NCHUNK * 256;    // 256
    int* cofs   = totG + 256;              // 257 (pad 288)
    int* rowptr = cofs + 288;              // N
    int* degi   = rowptr + NN;             // N
    float* dinv = (float*)(degi + NN);     // N
    unsigned int* pair = (unsigned int*)(dinv + NN);  // E  (25.6 MB)
    int* srcs   = (int*)(pair + EE);       // E  (25.6 MB)
    __half* t1  = (__half*)(srcs + EE);    // N*HD f16 (3.2 MB)
    __half* t2  = t1 + NN * HD;            // N*HD f16 (3.2 MB)

    // 3-pass no-claim radix partition by dst>>9 + per-bucket CSR
    chunk_hist_kernel<<<NCHUNK, 256, 0, stream>>>(dst, histG);
    colscan_kernel<<<256, 256, 0, stream>>>(histG, offsL, totG);
    scan_coarse_kernel<<<1, 256, 0, stream>>>(totG, cofs);
    coarse_scatter_kernel<<<NCHUNK, 512, 0, stream>>>(src, dst, histG, offsL, cofs, pair);
    bucket_build_kernel<<<NBUK, 1024, 0, stream>>>(pair, cofs, rowptr, degi, dinv, srcs);

    // layer 1: transform (f16 table), gather with fused epilogue -> t2 (f16)
    gemm1_kernel<<<(NN + 15) / 16, 256, 0, stream>>>(x, W1, dinv, t1);
    gather_relu_kernel<<<NN / 4, 256, 0, stream>>>(rowptr, degi, srcs,
                                                   (const __half2*)t1, dinv, b1,
                                                   (__half2*)t2);
    // layer 2: gather fused with dinv-scale + W2 transform
    gather_gemm2_kernel<<<NN / 4, 256, 0, stream>>>(rowptr, degi, srcs,
                                                    (const __half2*)t2, dinv, W2, b2, out);
}